// Round 13
// baseline (1314.498 us; speedup 1.0000x reference)
//
#include <hip/hip_runtime.h>
#include <hip/hip_bf16.h>
#include <stdint.h>

#define NB 32
#define NS 2048
#define ND 1024
#define NA 1024
#define MASK_NEG 1e30f

#define BM 256
#define BN 256
#define BK 64
#define NTILES 64  // 4 a-tiles x 16 K-tiles

typedef __attribute__((ext_vector_type(4))) float f32x4;
typedef __attribute__((ext_vector_type(8))) __bf16 bf16x8;

__device__ __forceinline__ void glds16(const void* g, void* l) {
  __builtin_amdgcn_global_load_lds(
      (const __attribute__((address_space(1))) uint32_t*)g,
      (__attribute__((address_space(3))) uint32_t*)(uintptr_t)l, 16, 0, 0);
}

// ---------------- zero scores (atomic accumulation target) ----------------
__global__ void zero_f32(float* __restrict__ p, int n) {
  int i = blockIdx.x * 256 + threadIdx.x;
  if (i < n) p[i] = 0.f;
}

// ---------------- fp32 -> bf16 bulk convert (W2 only, 2 MB) ----------------
__global__ __launch_bounds__(256) void cvt_bf16(const float* __restrict__ in,
                                                __bf16* __restrict__ out, int n8) {
  long i = blockIdx.x * 256 + threadIdx.x;
  const long stride = (long)gridDim.x * 256;
  for (; i < n8; i += stride) {
    f32x4 a = ((const f32x4*)in)[2 * i];
    f32x4 b = ((const f32x4*)in)[2 * i + 1];
    bf16x8 o;
#pragma unroll
    for (int j = 0; j < 4; ++j) { o[j] = (__bf16)a[j]; o[4 + j] = (__bf16)b[j]; }
    ((bf16x8*)out)[i] = o;
  }
}

// ---------------- w1q[b,a] = query[b,:] . W1[a,:]  (fp32) ----------------
__global__ __launch_bounds__(256) void w1q_kernel(const float* __restrict__ q,
                                                  const float* __restrict__ W1,
                                                  float* __restrict__ w1q) {
  const int b = blockIdx.x;
  const int a0 = blockIdx.y * 64;
  const int t = threadIdx.x;
  const int al = t >> 2;
  const int part = t & 3;
  const float* wrow = W1 + (size_t)(a0 + al) * ND + part * 256;
  const float* qrow = q + (size_t)b * ND + part * 256;
  float sum = 0.f;
#pragma unroll 8
  for (int i = 0; i < 256; i += 4) {
    float4 w = *reinterpret_cast<const float4*>(wrow + i);
    float4 x = *reinterpret_cast<const float4*>(qrow + i);
    sum += w.x * x.x + w.y * x.y + w.z * x.z + w.w * x.w;
  }
  __shared__ float red[256];
  red[t] = sum;
  __syncthreads();
  if (t < 64) {
    w1q[(size_t)b * NA + a0 + t] = red[t * 4] + red[t * 4 + 1] + red[t * 4 + 2] + red[t * 4 + 3];
  }
}

// ---------------- fused scores GEMM: 4 waves x 128x128, wave-internal pipeline ----------------
// 256 threads = 4 waves, 1 wave/SIMD (512-reg budget): acc 8x8 f32x4 (256 AGPR)
// + A/B frags (128 VGPR). Wave (wr,wc) owns rows wr*128.. x cols wc*128.. .
// LDS (R12-verified rings, 160 KB): A fp32 quarter-tiles (64r x 64k, 16 KB),
// ring-6, slot (4T+q)%6; B bf16 half-tiles (128r x 64k, 16 KB), ring-4,
// slot (2T+h)%4. Staging for T+1: q0,q1,B-h0,B-h1 at tile start; q2,q3 (which
// overwrite tile T's q0,q1 slots) after the mid-barrier (WAR: all T-reads
// forced complete by lgkm(0) before it -- R12 discipline). Only 2 barriers
// per K-tile; MFMAs are NOT pinned behind the reads: compiler-counted lgkm
// waits interleave the 48 ds_reads under the first 64-MFMA half (m97/m196).
// End-of-tile vmcnt(0) is ~free (1500-3000 cyc of flight).
// Swizzles (R12-verified): A store col16=(t&15)^((t>>4)&15), read unit
// (kk*8+ko*2(+1))^lrow; B store col16=(t&7)^((t>>3)&7), read (kk*4+ko)^(lrow&7).
__global__ __launch_bounds__(256, 1) void score_gemm(
    const float* __restrict__ keysf, const __bf16* __restrict__ W2b,
    const float* __restrict__ w1q, const float* __restrict__ vvec,
    float* __restrict__ scores) {
  __shared__ __attribute__((aligned(1024))) char ldsA[6 * 16384];  // 96 KB fp32 quarters
  __shared__ __attribute__((aligned(1024))) char ldsB[4 * 16384];  // 64 KB bf16 halves

  const int t = threadIdx.x;
  const int bs0 = blockIdx.x * BM;
  const int b = bs0 >> 11;  // / NS
  const int lane = t & 63;
  const int wid = t >> 6;
  const int wr = wid >> 1;   // 0..1: 128-row half of output
  const int wc = wid & 1;    // 0..1: 128-col half of output
  const int lrow = lane & 15;
  const int ko = lane >> 4;

  // staging maps (thread-linear LDS dest, inverse-swizzled global source)
  const int rowA = t >> 4;                   // 0..15 base row (16B units of 4 floats)
  const int scolA = (t & 15) ^ (rowA & 15);  // col16 unit to fetch
  const int rowB = t >> 3;                   // 0..31 base row
  const int scolB = (t & 7) ^ (rowB & 7);    // col16 unit (8 bf16)

  // fragment read units (pre-swizzled)
  const int sA00 = (ko * 2) ^ lrow, sA01 = (ko * 2 + 1) ^ lrow;
  const int sA10 = (8 + ko * 2) ^ lrow, sA11 = (8 + ko * 2 + 1) ^ lrow;
  const int sB0 = ko ^ (lrow & 7), sB1 = (4 + ko) ^ (lrow & 7);

  f32x4 acc[8][8];
#pragma unroll
  for (int mi = 0; mi < 8; ++mi)
#pragma unroll
    for (int ni = 0; ni < 8; ++ni) acc[mi][ni] = f32x4{0.f, 0.f, 0.f, 0.f};

  bf16x8 af[8][2], bfr[8][2];

#define STAGE_A(T, Q)                                                           \
  do {                                                                          \
    if ((T) < NTILES) {                                                         \
      const unsigned slot_ = (4u * (unsigned)(T) + (unsigned)(Q)) % 6u;         \
      char* d_ = ldsA + slot_ * 16384 + t * 16;                                 \
      const int kf_ = ((T)&15) * 64 + scolA * 4;                                \
      _Pragma("unroll") for (int j = 0; j < 4; ++j) {                           \
        glds16(keysf + (size_t)(bs0 + (Q)*64 + rowA + 16 * j) * ND + kf_,       \
               d_ + j * 4096);                                                  \
      }                                                                         \
    }                                                                           \
  } while (0)

#define STAGE_B(T, H)                                                           \
  do {                                                                          \
    if ((T) < NTILES) {                                                         \
      const unsigned slot_ = (2u * (unsigned)(T) + (unsigned)(H)) % 4u;         \
      char* d_ = ldsB + slot_ * 16384 + t * 16;                                 \
      const int ke_ = ((T)&15) * 64 + scolB * 8;                                \
      _Pragma("unroll") for (int j = 0; j < 4; ++j) {                           \
        glds16(W2b + (size_t)(((T) >> 4) * 256 + (H)*128 + rowB + 32 * j) * ND + ke_, \
               d_ + j * 4096);                                                  \
      }                                                                         \
    }                                                                           \
  } while (0)

#define SB_ __builtin_amdgcn_sched_barrier(0)
#define BAR __builtin_amdgcn_s_barrier()

  // ---- prologue: full tile 0; drain once ----
  STAGE_A(0, 0);
  STAGE_A(0, 1);
  STAGE_B(0, 0);
  STAGE_B(0, 1);
  STAGE_A(0, 2);
  STAGE_A(0, 3);
  __syncthreads();

  for (int tau = 0; tau < NTILES; ++tau) {
    // ---- stage S1 for tau+1: A q0,q1 + B h0,h1 (safe slots) ----
    STAGE_A(tau + 1, 0);
    STAGE_A(tau + 1, 1);
    STAGE_B(tau + 1, 0);
    STAGE_B(tau + 1, 1);

    // ---- frag reads for tau (compiler interleaves with MFMA half1) ----
    {
      const char* AbL = ldsA + ((4u * (unsigned)tau + 2u * wr) % 6u) * 16384;
      const char* AbH = ldsA + ((4u * (unsigned)tau + 2u * wr + 1u) % 6u) * 16384;
#pragma unroll
      for (int mi = 0; mi < 8; ++mi) {
        const char* Ab_ = (mi < 4) ? AbL : AbH;
        const int rb_ = ((mi & 3) * 16 + lrow) * 256;
        f32x4 l0 = *reinterpret_cast<const f32x4*>(Ab_ + rb_ + sA00 * 16);
        f32x4 l1 = *reinterpret_cast<const f32x4*>(Ab_ + rb_ + sA01 * 16);
        f32x4 h0 = *reinterpret_cast<const f32x4*>(Ab_ + rb_ + sA10 * 16);
        f32x4 h1 = *reinterpret_cast<const f32x4*>(Ab_ + rb_ + sA11 * 16);
#pragma unroll
        for (int j = 0; j < 4; ++j) {
          af[mi][0][j] = (__bf16)l0[j]; af[mi][0][4 + j] = (__bf16)l1[j];
          af[mi][1][j] = (__bf16)h0[j]; af[mi][1][4 + j] = (__bf16)h1[j];
        }
      }
      const char* Bb_ = ldsB + ((2u * (unsigned)tau + (unsigned)wc) % 4u) * 16384;
#pragma unroll
      for (int ni = 0; ni < 8; ++ni) {
        const int rb_ = (ni * 16 + lrow) * 128;
        bfr[ni][0] = *reinterpret_cast<const bf16x8*>(Bb_ + rb_ + sB0 * 16);
        bfr[ni][1] = *reinterpret_cast<const bf16x8*>(Bb_ + rb_ + sB1 * 16);
      }
    }

    // ---- MFMA half 1 (ni 0..3) ----
#pragma unroll
    for (int ni = 0; ni < 4; ++ni)
#pragma unroll
      for (int mi = 0; mi < 8; ++mi) {
        acc[mi][ni] = __builtin_amdgcn_mfma_f32_16x16x32_bf16(af[mi][0], bfr[ni][0], acc[mi][ni], 0, 0, 0);
        acc[mi][ni] = __builtin_amdgcn_mfma_f32_16x16x32_bf16(af[mi][1], bfr[ni][1], acc[mi][ni], 0, 0, 0);
      }
    asm volatile("s_waitcnt lgkmcnt(0)");
    SB_;
    BAR;  // mid: all tau-reads complete; q0,q1 slots may now be restaged

    // ---- stage S2 for tau+1: A q2,q3 (overwrite tau's q0,q1 slots) ----
    STAGE_A(tau + 1, 2);
    STAGE_A(tau + 1, 3);

    // ---- MFMA half 2 (ni 4..7) ----
#pragma unroll
    for (int ni = 4; ni < 8; ++ni)
#pragma unroll
      for (int mi = 0; mi < 8; ++mi) {
        acc[mi][ni] = __builtin_amdgcn_mfma_f32_16x16x32_bf16(af[mi][0], bfr[ni][0], acc[mi][ni], 0, 0, 0);
        acc[mi][ni] = __builtin_amdgcn_mfma_f32_16x16x32_bf16(af[mi][1], bfr[ni][1], acc[mi][ni], 0, 0, 0);
      }
    asm volatile("s_waitcnt vmcnt(0)");
    SB_;
    BAR;  // end: tau+1 fully staged and visible

    // ---- per-a-tile epilogue: tanh + v-weight -> atomic scores ----
    if ((tau & 15) == 15) {
      const int a0 = (tau >> 4) * BN;
      float w1v[8], vv[8];
#pragma unroll
      for (int ni = 0; ni < 8; ++ni) {
        const int a = a0 + wc * 128 + ni * 16 + lrow;
        w1v[ni] = w1q[(size_t)b * NA + a];
        vv[ni] = vvec[a];
      }
#pragma unroll
      for (int mi = 0; mi < 8; ++mi)
#pragma unroll
        for (int r = 0; r < 4; ++r) {
          float p = 0.f;
#pragma unroll
          for (int ni = 0; ni < 8; ++ni) {
            const float x = acc[mi][ni][r] + w1v[ni];
            const float e = __expf(2.f * x);
            p += (1.f - 2.f * __builtin_amdgcn_rcpf(e + 1.f)) * vv[ni];
          }
          p += __shfl_xor(p, 1);
          p += __shfl_xor(p, 2);
          p += __shfl_xor(p, 4);
          p += __shfl_xor(p, 8);
          if (lrow == 0)
            atomicAdd(&scores[bs0 + wr * 128 + mi * 16 + ko * 4 + r], p);
        }
#pragma unroll
      for (int mi = 0; mi < 8; ++mi)
#pragma unroll
        for (int ni = 0; ni < 8; ++ni) acc[mi][ni] = f32x4{0.f, 0.f, 0.f, 0.f};
    }
  }

#undef STAGE_A
#undef STAGE_B
#undef SB_
#undef BAR
}

// ---------------- masked softmax ----------------
__global__ __launch_bounds__(256) void softmax_kernel(const float* __restrict__ scores,
                                                      const int* __restrict__ mask,
                                                      float* __restrict__ out) {
  const int b = blockIdx.x;
  const int t = threadIdx.x;
  float sc[8];
  float mx = -3.4e38f;
#pragma unroll
  for (int j = 0; j < 8; ++j) {
    int i = t + j * 256;
    float s = scores[b * NS + i];
    if (mask[b * NS + i] == 0) s -= MASK_NEG;
    sc[j] = s;
    mx = fmaxf(mx, s);
  }
#pragma unroll
  for (int off = 1; off < 64; off <<= 1) mx = fmaxf(mx, __shfl_xor(mx, off));
  __shared__ float redm[4];
  __shared__ float reds[4];
  if ((t & 63) == 0) redm[t >> 6] = mx;
  __syncthreads();
  mx = fmaxf(fmaxf(redm[0], redm[1]), fmaxf(redm[2], redm[3]));
  float e[8];
  float sum = 0.f;
#pragma unroll
  for (int j = 0; j < 8; ++j) {
    e[j] = __expf(sc[j] - mx);
    sum += e[j];
  }
#pragma unroll
  for (int off = 1; off < 64; off <<= 1) sum += __shfl_xor(sum, off);
  if ((t & 63) == 0) reds[t >> 6] = sum;
  __syncthreads();
  sum = reds[0] + reds[1] + reds[2] + reds[3];
  float inv = 1.f / sum;
#pragma unroll
  for (int j = 0; j < 8; ++j) out[b * NS + t + j * 256] = e[j] * inv;
}

extern "C" void kernel_launch(void* const* d_in, const int* in_sizes, int n_in,
                              void* d_out, int out_size, void* d_ws, size_t ws_size,
                              hipStream_t stream) {
  const float* q = (const float*)d_in[0];
  const float* keysf = (const float*)d_in[1];
  const int* mask = (const int*)d_in[2];
  const float* W1 = (const float*)d_in[3];
  const float* W2f = (const float*)d_in[4];
  const float* v = (const float*)d_in[5];
  float* out = (float*)d_out;

  float* scores = (float*)d_ws;                                 // 256 KB
  float* w1q = scores + NB * NS;                                // 128 KB
  __bf16* W2b = (__bf16*)(w1q + NB * NA);                       // 2 MB

  zero_f32<<<NB * NS / 256, 256, 0, stream>>>(scores, NB * NS);
  cvt_bf16<<<512, 256, 0, stream>>>(W2f, W2b, NA * ND / 8);
  w1q_kernel<<<dim3(NB, NA / 64), 256, 0, stream>>>(q, W1, w1q);
  score_gemm<<<NB * NS / BM, 256, 0, stream>>>(keysf, W2b, w1q, v, scores);
  softmax_kernel<<<NB, 256, 0, stream>>>(scores, mask, out);
}

// Round 14
// 257.469 us; speedup vs baseline: 5.1055x; 5.1055x over previous
//
#include <hip/hip_runtime.h>
#include <hip/hip_bf16.h>
#include <stdint.h>

#define NB 32
#define NS 2048
#define ND 1024
#define NA 1024
#define MASK_NEG 1e30f

#define BM 256
#define BN 256
#define BK 64
#define NTILES 64  // 4 a-tiles x 16 K-tiles

typedef __attribute__((ext_vector_type(4))) float f32x4;
typedef __attribute__((ext_vector_type(8))) __bf16 bf16x8;

__device__ __forceinline__ void glds16(const void* g, void* l) {
  __builtin_amdgcn_global_load_lds(
      (const __attribute__((address_space(1))) uint32_t*)g,
      (__attribute__((address_space(3))) uint32_t*)(uintptr_t)l, 16, 0, 0);
}

// ---------------- zero scores (atomic accumulation target) ----------------
__global__ void zero_f32(float* __restrict__ p, int n) {
  int i = blockIdx.x * 256 + threadIdx.x;
  if (i < n) p[i] = 0.f;
}

// ---------------- fp32 -> bf16 bulk convert ----------------
__global__ __launch_bounds__(256) void cvt_bf16(const float* __restrict__ in,
                                                __bf16* __restrict__ out, int n8) {
  long i = blockIdx.x * 256 + threadIdx.x;
  const long stride = (long)gridDim.x * 256;
  for (; i < n8; i += stride) {
    f32x4 a = ((const f32x4*)in)[2 * i];
    f32x4 b = ((const f32x4*)in)[2 * i + 1];
    bf16x8 o;
#pragma unroll
    for (int j = 0; j < 4; ++j) { o[j] = (__bf16)a[j]; o[4 + j] = (__bf16)b[j]; }
    ((bf16x8*)out)[i] = o;
  }
}

// ---------------- w1q[b,a] = query[b,:] . W1[a,:]  (fp32) ----------------
__global__ __launch_bounds__(256) void w1q_kernel(const float* __restrict__ q,
                                                  const float* __restrict__ W1,
                                                  float* __restrict__ w1q) {
  const int b = blockIdx.x;
  const int a0 = blockIdx.y * 64;
  const int t = threadIdx.x;
  const int al = t >> 2;
  const int part = t & 3;
  const float* wrow = W1 + (size_t)(a0 + al) * ND + part * 256;
  const float* qrow = q + (size_t)b * ND + part * 256;
  float sum = 0.f;
#pragma unroll 8
  for (int i = 0; i < 256; i += 4) {
    float4 w = *reinterpret_cast<const float4*>(wrow + i);
    float4 x = *reinterpret_cast<const float4*>(qrow + i);
    sum += w.x * x.x + w.y * x.y + w.z * x.z + w.w * x.w;
  }
  __shared__ float red[256];
  red[t] = sum;
  __syncthreads();
  if (t < 64) {
    w1q[(size_t)b * NA + a0 + t] = red[t * 4] + red[t * 4 + 1] + red[t * 4 + 2] + red[t * 4 + 3];
  }
}

// ---------------- fused scores GEMM: deep-flight stagger (m201 N-depth) ----------------
// R8 base (8 waves 2Mx4N, 8 phases / 2 K-tiles, lgkm(0)-pinned MFMA clusters,
// R2-verified XOR swizzle) with ONE schedule change: staging flight depth.
// A (keys bf16): ring of 6 half-tiles [128r x 64k] (96 KB), slot (2T+h)%6 --
// lets A(t0+2) stage at ph3/ph4 (4+ phases before its forcing wait) instead of
// ring-4's 1-phase stagger. B (W2 bf16): ring-4 (64 KB), slot (2T+h)%4.
// Staging: ph1 B(t1,h0) | ph2 B(t1,h1) | ph3 A(t0+2,h0) | ph4 A(t0+2,h1) |
//          ph5 B(t0+2,h0) | ph6 B(t0+2,h1), A(t1+2,h0) | ph7 A(t1+2,h1)
// Waits: vmcnt(4) at ph4/ph8 only -- FIFO-audited: newest-4 are always the
// A-halves with later deadlines; all forced halves have >=2 (B/L2) or >=4
// (A/HBM) phases of flight. Tail it=31 drains (vmcnt(0)). WAR: ring-6 slot
// content is tile T-3, read-complete 5+ barriers before restage.
// LDS = 160 KB exactly -> w1q/v read from global in the per-a-tile epilogue;
// scores accumulated via atomicAdd (R12-proven pieces).
__global__ __launch_bounds__(512, 1) void score_gemm8(
    const __bf16* __restrict__ keysb, const __bf16* __restrict__ W2b,
    const float* __restrict__ w1q, const float* __restrict__ vvec,
    float* __restrict__ scores) {
  __shared__ __bf16 ldsA[6][128 * BK];  // 96 KB ring-6 halves
  __shared__ __bf16 ldsB[4][128 * BK];  // 64 KB ring-4 halves

  const int t = threadIdx.x;
  const int bs0 = blockIdx.x * BM;
  const int b = bs0 >> 11;  // / NS
  const int lane = t & 63;
  const int wid = t >> 6;
  const int wr = wid >> 2;   // 0..1: 128-row half of output
  const int wc = wid & 3;    // 0..3: 64-col quarter; B-half = wc>>1
  const int lrow = lane & 15;
  const int ko = lane >> 4;

  // staging lane geometry (R2-verified involution): 1 glds = 1 KB = 8 rows of
  // 128 B; this thread stages rows wid*16+j*8+srow (j=0,1) of each half-tile.
  const int srow = lane >> 3;
  const int scol = (lane & 7) ^ srow;
  const size_t aoffT = (size_t)(bs0 + wid * 16 + srow) * ND + scol * 8;
  const size_t boffT = (size_t)(wid * 16 + srow) * ND + scol * 8;

  // fragment read slots (pre-swizzled; row offsets are multiples of 8)
  const int sl0 = ko ^ (lrow & 7);
  const int sl1 = (4 + ko) ^ (lrow & 7);

#define STAGE_A(T, H)                                                           \
  do {                                                                          \
    if ((T) < NTILES) {                                                         \
      const unsigned slot_ = (2u * (unsigned)(T) + (unsigned)(H)) % 6u;         \
      char* d_ = (char*)ldsA + (slot_ << 14) + wid * 2048;                      \
      const size_t g_ = aoffT + (size_t)((H)*128) * ND + (size_t)(((T)&15) * BK); \
      glds16(keysb + g_, d_);                                                   \
      glds16(keysb + g_ + (size_t)8 * ND, d_ + 1024);                           \
    }                                                                           \
  } while (0)

#define STAGE_B(T, H)                                                           \
  do {                                                                          \
    if ((T) < NTILES) {                                                         \
      const unsigned slot_ = (2u * (unsigned)(T) + (unsigned)(H)) % 4u;         \
      char* d_ = (char*)ldsB + (slot_ << 14) + wid * 2048;                      \
      const size_t g_ = boffT + (size_t)(((T) >> 4) * 256 + (H)*128) * ND +     \
                        (size_t)(((T)&15) * BK);                                \
      glds16(W2b + g_, d_);                                                     \
      glds16(W2b + g_ + (size_t)8 * ND, d_ + 1024);                             \
    }                                                                           \
  } while (0)

#define SB __builtin_amdgcn_sched_barrier(0)
#define P1 __builtin_amdgcn_s_setprio(1)
#define P0 __builtin_amdgcn_s_setprio(0)
#define BAR __builtin_amdgcn_s_barrier()

  // PHASE: stage -> reads (af fresh on N_==0; reused on N_==1) -> BAR ->
  // lgkm(0) -> 16 MFMA -> [vmcnt(4) at ph4/ph8; tail drains] -> BAR.
#define PHASE(TL, M_, N_, STAGE_STMT, WM)                                       \
  do {                                                                          \
    STAGE_STMT;                                                                 \
    if ((N_) == 0) {                                                            \
      const char* Ab_ =                                                         \
          (const char*)ldsA + (((2u * (unsigned)(TL) + (unsigned)wr) % 6u) << 14); \
      _Pragma("unroll") for (int mi = 0; mi < 4; ++mi) {                        \
        const int ra_ = (((M_)*4 + mi) * 16 + lrow) * 128;                      \
        af[mi][0] = *reinterpret_cast<const bf16x8*>(Ab_ + ra_ + sl0 * 16);     \
        af[mi][1] = *reinterpret_cast<const bf16x8*>(Ab_ + ra_ + sl1 * 16);     \
      }                                                                         \
    }                                                                           \
    {                                                                           \
      const char* Bb_ =                                                         \
          (const char*)ldsB + (((2u * (unsigned)(TL) + (unsigned)(wc >> 1)) % 4u) << 14); \
      _Pragma("unroll") for (int nq = 0; nq < 2; ++nq) {                        \
        const int rb_ = (((wc & 1) * 4 + (N_)*2 + nq) * 16 + lrow) * 128;       \
        bfr[nq][0] = *reinterpret_cast<const bf16x8*>(Bb_ + rb_ + sl0 * 16);    \
        bfr[nq][1] = *reinterpret_cast<const bf16x8*>(Bb_ + rb_ + sl1 * 16);    \
      }                                                                         \
    }                                                                           \
    BAR;                                                                        \
    asm volatile("s_waitcnt lgkmcnt(0)");                                       \
    SB;                                                                         \
    P1;                                                                         \
    _Pragma("unroll") for (int mi = 0; mi < 4; ++mi)                            \
        _Pragma("unroll") for (int nq = 0; nq < 2; ++nq) {                      \
      acc[(M_)*4 + mi][(N_)*2 + nq] = __builtin_amdgcn_mfma_f32_16x16x32_bf16(  \
          af[mi][0], bfr[nq][0], acc[(M_)*4 + mi][(N_)*2 + nq], 0, 0, 0);       \
      acc[(M_)*4 + mi][(N_)*2 + nq] = __builtin_amdgcn_mfma_f32_16x16x32_bf16(  \
          af[mi][1], bfr[nq][1], acc[(M_)*4 + mi][(N_)*2 + nq], 0, 0, 0);       \
    }                                                                           \
    P0;                                                                         \
    if (WM) {                                                                   \
      if (it != 31) { asm volatile("s_waitcnt vmcnt(4)"); }                     \
      else { asm volatile("s_waitcnt vmcnt(0)"); }                              \
      SB;                                                                       \
    }                                                                           \
    BAR;                                                                        \
  } while (0)

  f32x4 acc[8][4];
#pragma unroll
  for (int mi = 0; mi < 8; ++mi)
#pragma unroll
    for (int ni = 0; ni < 4; ++ni) acc[mi][ni] = f32x4{0.f, 0.f, 0.f, 0.f};

  bf16x8 af[4][2], bfr[2][2];

  // ---- prologue: A(0,*), A(1,*), B(0,*); drain once ----
  STAGE_A(0, 0);
  STAGE_A(0, 1);
  STAGE_A(1, 0);
  STAGE_A(1, 1);
  STAGE_B(0, 0);
  STAGE_B(0, 1);
  __syncthreads();

  for (int it = 0; it < 32; ++it) {
    const int t0 = 2 * it, t1 = 2 * it + 1;
    PHASE(t0, 0, 0, STAGE_B(t1, 0), 0);                        // ph1
    PHASE(t0, 0, 1, STAGE_B(t1, 1), 0);                        // ph2
    PHASE(t0, 1, 0, STAGE_A(t0 + 2, 0), 0);                    // ph3
    PHASE(t0, 1, 1, STAGE_A(t0 + 2, 1), 1);                    // ph4 + vmcnt(4)
    PHASE(t1, 0, 0, STAGE_B(t0 + 2, 0), 0);                    // ph5
    PHASE(t1, 0, 1, { STAGE_B(t0 + 2, 1); STAGE_A(t1 + 2, 0); }, 0);  // ph6
    PHASE(t1, 1, 0, STAGE_A(t1 + 2, 1), 0);                    // ph7
    PHASE(t1, 1, 1, {}, 1);                                    // ph8 + vmcnt(4)

    // ---- per-a-tile epilogue: tanh + v-weight -> atomic scores ----
    if ((it & 7) == 7) {
      const int a0 = (it >> 3) * BN;
      float w1v[4], vv[4];
#pragma unroll
      for (int ni = 0; ni < 4; ++ni) {
        const int a = a0 + wc * 64 + ni * 16 + lrow;
        w1v[ni] = w1q[(size_t)b * NA + a];
        vv[ni] = vvec[a];
      }
#pragma unroll
      for (int mi = 0; mi < 8; ++mi)
#pragma unroll
        for (int r = 0; r < 4; ++r) {
          float p = 0.f;
#pragma unroll
          for (int ni = 0; ni < 4; ++ni) {
            const float x = acc[mi][ni][r] + w1v[ni];
            const float e = __expf(2.f * x);
            p += (1.f - 2.f * __builtin_amdgcn_rcpf(e + 1.f)) * vv[ni];
          }
          p += __shfl_xor(p, 1);
          p += __shfl_xor(p, 2);
          p += __shfl_xor(p, 4);
          p += __shfl_xor(p, 8);
          if (lrow == 0)
            atomicAdd(&scores[bs0 + wr * 128 + mi * 16 + ko * 4 + r], p);
        }
#pragma unroll
      for (int mi = 0; mi < 8; ++mi)
#pragma unroll
        for (int ni = 0; ni < 4; ++ni) acc[mi][ni] = f32x4{0.f, 0.f, 0.f, 0.f};
    }
  }

#undef STAGE_A
#undef STAGE_B
#undef PHASE
#undef SB
#undef P1
#undef P0
#undef BAR
}

// ---------------- masked softmax ----------------
__global__ __launch_bounds__(256) void softmax_kernel(const float* __restrict__ scores,
                                                      const int* __restrict__ mask,
                                                      float* __restrict__ out) {
  const int b = blockIdx.x;
  const int t = threadIdx.x;
  float sc[8];
  float mx = -3.4e38f;
#pragma unroll
  for (int j = 0; j < 8; ++j) {
    int i = t + j * 256;
    float s = scores[b * NS + i];
    if (mask[b * NS + i] == 0) s -= MASK_NEG;
    sc[j] = s;
    mx = fmaxf(mx, s);
  }
#pragma unroll
  for (int off = 1; off < 64; off <<= 1) mx = fmaxf(mx, __shfl_xor(mx, off));
  __shared__ float redm[4];
  __shared__ float reds[4];
  if ((t & 63) == 0) redm[t >> 6] = mx;
  __syncthreads();
  mx = fmaxf(fmaxf(redm[0], redm[1]), fmaxf(redm[2], redm[3]));
  float e[8];
  float sum = 0.f;
#pragma unroll
  for (int j = 0; j < 8; ++j) {
    e[j] = __expf(sc[j] - mx);
    sum += e[j];
  }
#pragma unroll
  for (int off = 1; off < 64; off <<= 1) sum += __shfl_xor(sum, off);
  if ((t & 63) == 0) reds[t >> 6] = sum;
  __syncthreads();
  sum = reds[0] + reds[1] + reds[2] + reds[3];
  float inv = 1.f / sum;
#pragma unroll
  for (int j = 0; j < 8; ++j) out[b * NS + t + j * 256] = e[j] * inv;
}

extern "C" void kernel_launch(void* const* d_in, const int* in_sizes, int n_in,
                              void* d_out, int out_size, void* d_ws, size_t ws_size,
                              hipStream_t stream) {
  const float* q = (const float*)d_in[0];
  const float* keysf = (const float*)d_in[1];
  const int* mask = (const int*)d_in[2];
  const float* W1 = (const float*)d_in[3];
  const float* W2f = (const float*)d_in[4];
  const float* v = (const float*)d_in[5];
  float* out = (float*)d_out;

  float* scores = (float*)d_ws;                                 // 256 KB
  float* w1q = scores + NB * NS;                                // 128 KB
  __bf16* W2b = (__bf16*)(w1q + NB * NA);                       // 2 MB
  __bf16* keysb = (__bf16*)((char*)W2b + (size_t)NA * ND * 2);  // 128 MB

  zero_f32<<<NB * NS / 256, 256, 0, stream>>>(scores, NB * NS);
  cvt_bf16<<<512, 256, 0, stream>>>(W2f, W2b, NA * ND / 8);
  cvt_bf16<<<2048, 256, 0, stream>>>(keysf, keysb, (int)((size_t)NB * NS * ND / 8));
  w1q_kernel<<<dim3(NB, NA / 64), 256, 0, stream>>>(q, W1, w1q);
  score_gemm8<<<NB * NS / BM, 512, 0, stream>>>(keysb, W2b, w1q, v, scores);
  softmax_kernel<<<NB, 256, 0, stream>>>(scores, mask, out);
}

// Round 15
// 250.021 us; speedup vs baseline: 5.2575x; 1.0298x over previous
//
#include <hip/hip_runtime.h>
#include <hip/hip_bf16.h>
#include <stdint.h>

#define NB 32
#define NS 2048
#define ND 1024
#define NA 1024
#define MASK_NEG 1e30f

#define BM 256
#define BN 256
#define BK 64
#define NTILES 64  // 4 a-tiles x 16 K-tiles

typedef __attribute__((ext_vector_type(4))) float f32x4;
typedef __attribute__((ext_vector_type(8))) __bf16 bf16x8;

__device__ __forceinline__ void glds16(const void* g, void* l) {
  __builtin_amdgcn_global_load_lds(
      (const __attribute__((address_space(1))) uint32_t*)g,
      (__attribute__((address_space(3))) uint32_t*)(uintptr_t)l, 16, 0, 0);
}

// ---------------- zero scores (atomic accumulation target) ----------------
__global__ void zero_f32(float* __restrict__ p, int n) {
  int i = blockIdx.x * 256 + threadIdx.x;
  if (i < n) p[i] = 0.f;
}

// ---------------- fp32 -> bf16 bulk convert (W2 only, 2 MB) ----------------
__global__ __launch_bounds__(256) void cvt_bf16(const float* __restrict__ in,
                                                __bf16* __restrict__ out, int n8) {
  long i = blockIdx.x * 256 + threadIdx.x;
  const long stride = (long)gridDim.x * 256;
  for (; i < n8; i += stride) {
    f32x4 a = ((const f32x4*)in)[2 * i];
    f32x4 b = ((const f32x4*)in)[2 * i + 1];
    bf16x8 o;
#pragma unroll
    for (int j = 0; j < 4; ++j) { o[j] = (__bf16)a[j]; o[4 + j] = (__bf16)b[j]; }
    ((bf16x8*)out)[i] = o;
  }
}

// ---------------- w1q[b,a] = query[b,:] . W1[a,:]  (fp32) ----------------
__global__ __launch_bounds__(256) void w1q_kernel(const float* __restrict__ q,
                                                  const float* __restrict__ W1,
                                                  float* __restrict__ w1q) {
  const int b = blockIdx.x;
  const int a0 = blockIdx.y * 64;
  const int t = threadIdx.x;
  const int al = t >> 2;
  const int part = t & 3;
  const float* wrow = W1 + (size_t)(a0 + al) * ND + part * 256;
  const float* qrow = q + (size_t)b * ND + part * 256;
  float sum = 0.f;
#pragma unroll 8
  for (int i = 0; i < 256; i += 4) {
    float4 w = *reinterpret_cast<const float4*>(wrow + i);
    float4 x = *reinterpret_cast<const float4*>(qrow + i);
    sum += w.x * x.x + w.y * x.y + w.z * x.z + w.w * x.w;
  }
  __shared__ float red[256];
  red[t] = sum;
  __syncthreads();
  if (t < 64) {
    w1q[(size_t)b * NA + a0 + t] = red[t * 4] + red[t * 4 + 1] + red[t * 4 + 2] + red[t * 4 + 3];
  }
}

// ---------------- fused scores GEMM: in-kernel keys cvt (T14 async split) ----------------
// R14 base (8 waves, ring-6 A / ring-4 B, R2-verified swizzle, atomicAdd
// epilogue, 160 KB LDS). A-half writes move to ph1/3/5/7 (slot (2T+h)%6).
// Tiles T<16 (first a-tile pass): A staged by REG PATH -- fp32 keys loaded 2
// phases early (la[4], 16 VGPR), cvt->bf16, ds_write the same swizzled bytes
// glds would produce, plus side-store bf16 to keysb. Tiles T>=16: glds from
// keysb (L3-resident). Kills the standalone 65us keys-cvt kernel.
// Waits: mode-R (it<7) vmcnt(0)@ph4/ph8 (every drained unit >=2 phases old or
// a store); mode-G vmcnt(2) (FIFO-audited: leaves only the newest A-half, all
// forced units >=2-phase flight); it==31 drains. Stores complete before the
// first keysb glds (it=7 ph3) via it=6 ph8's vmcnt(0) + barriers; same-XCD L2.
__global__ __launch_bounds__(512, 1) void score_gemm8(
    const float* __restrict__ keysf, __bf16* __restrict__ keysb,
    const __bf16* __restrict__ W2b,
    const float* __restrict__ w1q, const float* __restrict__ vvec,
    float* __restrict__ scores) {
  __shared__ __bf16 ldsA[6][128 * BK];  // 96 KB ring-6 halves
  __shared__ __bf16 ldsB[4][128 * BK];  // 64 KB ring-4 halves

  const int t = threadIdx.x;
  const int bs0 = blockIdx.x * BM;
  const int b = bs0 >> 11;  // / NS
  const int lane = t & 63;
  const int wid = t >> 6;
  const int wr = wid >> 2;   // 0..1: 128-row half of output
  const int wc = wid & 3;    // 0..3: 64-col quarter; B-half = wc>>1
  const int lrow = lane & 15;
  const int ko = lane >> 4;

  // staging lane geometry (R2-verified involution)
  const int srow = lane >> 3;
  const int scol = (lane & 7) ^ srow;
  const size_t boffT = (size_t)(wid * 16 + srow) * ND + scol * 8;

  // fragment read slots (pre-swizzled)
  const int sl0 = ko ^ (lrow & 7);
  const int sl1 = (4 + ko) ^ (lrow & 7);

  f32x4 la[4];  // one in-flight fp32 A-half batch (16 VGPR)

#define ALOAD(T, H)                                                             \
  do {                                                                          \
    if ((T) < 16) {                                                             \
      const float* gp_ = keysf +                                                \
          (size_t)(bs0 + (H)*128 + wid * 16 + srow) * ND + ((T)&15) * 64 + scol * 8; \
      la[0] = *reinterpret_cast<const f32x4*>(gp_);                             \
      la[1] = *reinterpret_cast<const f32x4*>(gp_ + 4);                         \
      la[2] = *reinterpret_cast<const f32x4*>(gp_ + (size_t)8 * ND);            \
      la[3] = *reinterpret_cast<const f32x4*>(gp_ + (size_t)8 * ND + 4);        \
    }                                                                           \
  } while (0)

#define AWRITE(T, H)                                                            \
  do {                                                                          \
    if ((T) < NTILES) {                                                         \
      char* du_ = (char*)ldsA + (((2u * (unsigned)(T) + (unsigned)(H)) % 6u) << 14) + \
                  wid * 2048;                                                   \
      if ((T) < 16) {                                                           \
        bf16x8 o0_, o1_;                                                        \
        _Pragma("unroll") for (int j = 0; j < 4; ++j) {                         \
          o0_[j] = (__bf16)la[0][j]; o0_[4 + j] = (__bf16)la[1][j];             \
          o1_[j] = (__bf16)la[2][j]; o1_[4 + j] = (__bf16)la[3][j];             \
        }                                                                       \
        *reinterpret_cast<bf16x8*>(du_ + lane * 16) = o0_;                      \
        *reinterpret_cast<bf16x8*>(du_ + 1024 + lane * 16) = o1_;               \
        __bf16* gs_ = keysb +                                                   \
            (size_t)(bs0 + (H)*128 + wid * 16 + srow) * ND + ((T)&15) * 64 + scol * 8; \
        *reinterpret_cast<bf16x8*>(gs_) = o0_;                                  \
        *reinterpret_cast<bf16x8*>(gs_ + (size_t)8 * ND) = o1_;                 \
      } else {                                                                  \
        const size_t g_ = (size_t)(bs0 + (H)*128 + wid * 16 + srow) * ND +      \
                          ((T)&15) * 64 + scol * 8;                             \
        glds16(keysb + g_, du_);                                                \
        glds16(keysb + g_ + (size_t)8 * ND, du_ + 1024);                        \
      }                                                                         \
    }                                                                           \
  } while (0)

#define STAGE_B(T, H)                                                           \
  do {                                                                          \
    if ((T) < NTILES) {                                                         \
      char* d_ = (char*)ldsB + (((2u * (unsigned)(T) + (unsigned)(H)) % 4u) << 14) + \
                 wid * 2048;                                                    \
      const size_t g_ = boffT + (size_t)(((T) >> 4) * 256 + (H)*128) * ND +     \
                        (size_t)(((T)&15) * BK);                                \
      glds16(W2b + g_, d_);                                                     \
      glds16(W2b + g_ + (size_t)8 * ND, d_ + 1024);                             \
    }                                                                           \
  } while (0)

#define SB __builtin_amdgcn_sched_barrier(0)
#define P1 __builtin_amdgcn_s_setprio(1)
#define P0 __builtin_amdgcn_s_setprio(0)
#define BAR __builtin_amdgcn_s_barrier()

#define PHASE(TL, M_, N_, PRE_STMT, WM)                                         \
  do {                                                                          \
    PRE_STMT;                                                                   \
    if ((N_) == 0) {                                                            \
      const char* Ab_ =                                                         \
          (const char*)ldsA + (((2u * (unsigned)(TL) + (unsigned)wr) % 6u) << 14); \
      _Pragma("unroll") for (int mi = 0; mi < 4; ++mi) {                        \
        const int ra_ = (((M_)*4 + mi) * 16 + lrow) * 128;                      \
        af[mi][0] = *reinterpret_cast<const bf16x8*>(Ab_ + ra_ + sl0 * 16);     \
        af[mi][1] = *reinterpret_cast<const bf16x8*>(Ab_ + ra_ + sl1 * 16);     \
      }                                                                         \
    }                                                                           \
    {                                                                           \
      const char* Bb_ =                                                         \
          (const char*)ldsB + (((2u * (unsigned)(TL) + (unsigned)(wc >> 1)) % 4u) << 14); \
      _Pragma("unroll") for (int nq = 0; nq < 2; ++nq) {                        \
        const int rb_ = (((wc & 1) * 4 + (N_)*2 + nq) * 16 + lrow) * 128;       \
        bfr[nq][0] = *reinterpret_cast<const bf16x8*>(Bb_ + rb_ + sl0 * 16);    \
        bfr[nq][1] = *reinterpret_cast<const bf16x8*>(Bb_ + rb_ + sl1 * 16);    \
      }                                                                         \
    }                                                                           \
    BAR;                                                                        \
    asm volatile("s_waitcnt lgkmcnt(0)");                                       \
    SB;                                                                         \
    P1;                                                                         \
    _Pragma("unroll") for (int mi = 0; mi < 4; ++mi)                            \
        _Pragma("unroll") for (int nq = 0; nq < 2; ++nq) {                      \
      acc[(M_)*4 + mi][(N_)*2 + nq] = __builtin_amdgcn_mfma_f32_16x16x32_bf16(  \
          af[mi][0], bfr[nq][0], acc[(M_)*4 + mi][(N_)*2 + nq], 0, 0, 0);       \
      acc[(M_)*4 + mi][(N_)*2 + nq] = __builtin_amdgcn_mfma_f32_16x16x32_bf16(  \
          af[mi][1], bfr[nq][1], acc[(M_)*4 + mi][(N_)*2 + nq], 0, 0, 0);       \
    }                                                                           \
    P0;                                                                         \
    if (WM) {                                                                   \
      if (it < 7 || it == 31) { asm volatile("s_waitcnt vmcnt(0)"); }           \
      else { asm volatile("s_waitcnt vmcnt(2)"); }                              \
      SB;                                                                       \
    }                                                                           \
    BAR;                                                                        \
  } while (0)

  f32x4 acc[8][4];
#pragma unroll
  for (int mi = 0; mi < 8; ++mi)
#pragma unroll
    for (int ni = 0; ni < 4; ++ni) acc[mi][ni] = f32x4{0.f, 0.f, 0.f, 0.f};

  bf16x8 af[4][2], bfr[2][2];

  // ---- prologue: A(0,*), A(1,h0) via reg-cvt; B(0) glds; la <- L(1,h1) ----
  ALOAD(0, 0); AWRITE(0, 0);
  ALOAD(0, 1); AWRITE(0, 1);
  ALOAD(1, 0); AWRITE(1, 0);
  STAGE_B(0, 0);
  STAGE_B(0, 1);
  ALOAD(1, 1);       // consumed at it=0 ph1
  __syncthreads();   // drains vmcnt/lgkm (stores too)

  for (int it = 0; it < 32; ++it) {
    const int t0 = 2 * it, t1 = 2 * it + 1;
    PHASE(t0, 0, 0, { AWRITE(t1, 1); STAGE_B(t1, 0); ALOAD(t0 + 2, 0); }, 0);  // ph1
    PHASE(t0, 0, 1, { STAGE_B(t1, 1); }, 0);                                   // ph2
    PHASE(t0, 1, 0, { AWRITE(t0 + 2, 0); ALOAD(t0 + 2, 1); }, 0);              // ph3
    PHASE(t0, 1, 1, {}, 1);                                                    // ph4 + wait
    PHASE(t1, 0, 0, { AWRITE(t0 + 2, 1); STAGE_B(t0 + 2, 0); ALOAD(t1 + 2, 0); }, 0);  // ph5
    PHASE(t1, 0, 1, { STAGE_B(t0 + 2, 1); }, 0);                               // ph6
    PHASE(t1, 1, 0, { AWRITE(t1 + 2, 0); ALOAD(t1 + 2, 1); }, 0);              // ph7
    PHASE(t1, 1, 1, {}, 1);                                                    // ph8 + wait

    // ---- per-a-tile epilogue: tanh + v-weight -> atomic scores ----
    if ((it & 7) == 7) {
      const int a0 = (it >> 3) * BN;
      float w1v[4], vv[4];
#pragma unroll
      for (int ni = 0; ni < 4; ++ni) {
        const int a = a0 + wc * 64 + ni * 16 + lrow;
        w1v[ni] = w1q[(size_t)b * NA + a];
        vv[ni] = vvec[a];
      }
#pragma unroll
      for (int mi = 0; mi < 8; ++mi)
#pragma unroll
        for (int r = 0; r < 4; ++r) {
          float p = 0.f;
#pragma unroll
          for (int ni = 0; ni < 4; ++ni) {
            const float x = acc[mi][ni][r] + w1v[ni];
            const float e = __expf(2.f * x);
            p += (1.f - 2.f * __builtin_amdgcn_rcpf(e + 1.f)) * vv[ni];
          }
          p += __shfl_xor(p, 1);
          p += __shfl_xor(p, 2);
          p += __shfl_xor(p, 4);
          p += __shfl_xor(p, 8);
          if (lrow == 0)
            atomicAdd(&scores[bs0 + wr * 128 + mi * 16 + ko * 4 + r], p);
        }
#pragma unroll
      for (int mi = 0; mi < 8; ++mi)
#pragma unroll
        for (int ni = 0; ni < 4; ++ni) acc[mi][ni] = f32x4{0.f, 0.f, 0.f, 0.f};
    }
  }

#undef ALOAD
#undef AWRITE
#undef STAGE_B
#undef PHASE
#undef SB
#undef P1
#undef P0
#undef BAR
}

// ---------------- masked softmax ----------------
__global__ __launch_bounds__(256) void softmax_kernel(const float* __restrict__ scores,
                                                      const int* __restrict__ mask,
                                                      float* __restrict__ out) {
  const int b = blockIdx.x;
  const int t = threadIdx.x;
  float sc[8];
  float mx = -3.4e38f;
#pragma unroll
  for (int j = 0; j < 8; ++j) {
    int i = t + j * 256;
    float s = scores[b * NS + i];
    if (mask[b * NS + i] == 0) s -= MASK_NEG;
    sc[j] = s;
    mx = fmaxf(mx, s);
  }
#pragma unroll
  for (int off = 1; off < 64; off <<= 1) mx = fmaxf(mx, __shfl_xor(mx, off));
  __shared__ float redm[4];
  __shared__ float reds[4];
  if ((t & 63) == 0) redm[t >> 6] = mx;
  __syncthreads();
  mx = fmaxf(fmaxf(redm[0], redm[1]), fmaxf(redm[2], redm[3]));
  float e[8];
  float sum = 0.f;
#pragma unroll
  for (int j = 0; j < 8; ++j) {
    e[j] = __expf(sc[j] - mx);
    sum += e[j];
  }
#pragma unroll
  for (int off = 1; off < 64; off <<= 1) sum += __shfl_xor(sum, off);
  if ((t & 63) == 0) reds[t >> 6] = sum;
  __syncthreads();
  sum = reds[0] + reds[1] + reds[2] + reds[3];
  float inv = 1.f / sum;
#pragma unroll
  for (int j = 0; j < 8; ++j) out[b * NS + t + j * 256] = e[j] * inv;
}

extern "C" void kernel_launch(void* const* d_in, const int* in_sizes, int n_in,
                              void* d_out, int out_size, void* d_ws, size_t ws_size,
                              hipStream_t stream) {
  const float* q = (const float*)d_in[0];
  const float* keysf = (const float*)d_in[1];
  const int* mask = (const int*)d_in[2];
  const float* W1 = (const float*)d_in[3];
  const float* W2f = (const float*)d_in[4];
  const float* v = (const float*)d_in[5];
  float* out = (float*)d_out;

  float* scores = (float*)d_ws;                                 // 256 KB
  float* w1q = scores + NB * NS;                                // 128 KB
  __bf16* W2b = (__bf16*)(w1q + NB * NA);                       // 2 MB
  __bf16* keysb = (__bf16*)((char*)W2b + (size_t)NA * ND * 2);  // 128 MB

  zero_f32<<<NB * NS / 256, 256, 0, stream>>>(scores, NB * NS);
  cvt_bf16<<<512, 256, 0, stream>>>(W2f, W2b, NA * ND / 8);
  w1q_kernel<<<dim3(NB, NA / 64), 256, 0, stream>>>(q, W1, w1q);
  score_gemm8<<<NB * NS / BM, 512, 0, stream>>>(keysf, keysb, W2b, w1q, v, scores);
  softmax_kernel<<<NB, 256, 0, stream>>>(scores, mask, out);
}

// Round 16
// 221.226 us; speedup vs baseline: 5.9419x; 1.1302x over previous
//
#include <hip/hip_runtime.h>
#include <hip/hip_bf16.h>
#include <stdint.h>

#define NB 32
#define NS 2048
#define ND 1024
#define NA 1024
#define MASK_NEG 1e30f

#define BM 256
#define BN 256
#define BK 64
#define NTILES 64  // 4 a-tiles x 16 K-tiles

typedef __attribute__((ext_vector_type(4))) float f32x4;
typedef __attribute__((ext_vector_type(8))) __bf16 bf16x8;

__device__ __forceinline__ void glds16(const void* g, void* l) {
  __builtin_amdgcn_global_load_lds(
      (const __attribute__((address_space(1))) uint32_t*)g,
      (__attribute__((address_space(3))) uint32_t*)(uintptr_t)l, 16, 0, 0);
}

// ---------------- zero scores (atomic accumulation target) ----------------
__global__ void zero_f32(float* __restrict__ p, int n) {
  int i = blockIdx.x * 256 + threadIdx.x;
  if (i < n) p[i] = 0.f;
}

// ---------------- fp32 -> bf16 bulk convert (W2 only, 2 MB) ----------------
__global__ __launch_bounds__(256) void cvt_bf16(const float* __restrict__ in,
                                                __bf16* __restrict__ out, int n8) {
  long i = blockIdx.x * 256 + threadIdx.x;
  const long stride = (long)gridDim.x * 256;
  for (; i < n8; i += stride) {
    f32x4 a = ((const f32x4*)in)[2 * i];
    f32x4 b = ((const f32x4*)in)[2 * i + 1];
    bf16x8 o;
#pragma unroll
    for (int j = 0; j < 4; ++j) { o[j] = (__bf16)a[j]; o[4 + j] = (__bf16)b[j]; }
    ((bf16x8*)out)[i] = o;
  }
}

// ---------------- w1q[b,a] = query[b,:] . W1[a,:]  (fp32) ----------------
__global__ __launch_bounds__(256) void w1q_kernel(const float* __restrict__ q,
                                                  const float* __restrict__ W1,
                                                  float* __restrict__ w1q) {
  const int b = blockIdx.x;
  const int a0 = blockIdx.y * 64;
  const int t = threadIdx.x;
  const int al = t >> 2;
  const int part = t & 3;
  const float* wrow = W1 + (size_t)(a0 + al) * ND + part * 256;
  const float* qrow = q + (size_t)b * ND + part * 256;
  float sum = 0.f;
#pragma unroll 8
  for (int i = 0; i < 256; i += 4) {
    float4 w = *reinterpret_cast<const float4*>(wrow + i);
    float4 x = *reinterpret_cast<const float4*>(qrow + i);
    sum += w.x * x.x + w.y * x.y + w.z * x.z + w.w * x.w;
  }
  __shared__ float red[256];
  red[t] = sum;
  __syncthreads();
  if (t < 64) {
    w1q[(size_t)b * NA + a0 + t] = red[t * 4] + red[t * 4 + 1] + red[t * 4 + 2] + red[t * 4 + 3];
  }
}

// ---------------- fused scores GEMM: fp32-direct A, 4Mx2N waves ----------------
// R12 base (fp32 keys staged straight to LDS via glds16 -- no keys cvt kernel,
// no keysb; A fp32 quarter-tiles [64r x 64k = 16 KB] ring-6 slot (4T+q)%6;
// B bf16 half-tiles [128r x 64k = 16 KB] ring-4 slot (2T+h)%4; 160 KB LDS;
// w1q/v from global; atomicAdd scores) with ONE change: wave geometry 2Mx4N ->
// 4Mx2N (wave = 64 rows x 128 cols; wr = A-quarter index). This halves A-side
// LDS frag re-reads: 384 -> 256 KB/CU/K-tile.
// Reads: wave reads ALL 16 A-frags of slot (4tau+wr)%6 at ph1 (slot then
// read-complete -> ph2 restage of (tau,q0/q1) slots is WAR-safe, 1 barrier
// after); bfr (2 frags) fresh per phase from slot (2tau+wc)%4.
// Staging (issue-early, R6 discipline): ph1 {A q0,q1; B h0}, ph2 {A q2,q3;
// B h1}; single vmcnt(0) at ph4-end (2-3 phases of flight); tail no-ops.
// Swizzles (R12-verified): A store col16=(t&15)^((t>>4)&15), read unit
// (ko*2(+1))^lrow / (8+ko*2(+1))^lrow; B store (t&7)^((t>>3)&7), read
// (kk*4+ko)^(lrow&7).
__global__ __launch_bounds__(512, 1) void score_gemm(
    const float* __restrict__ keysf, const __bf16* __restrict__ W2b,
    const float* __restrict__ w1q, const float* __restrict__ vvec,
    float* __restrict__ scores) {
  __shared__ __attribute__((aligned(1024))) char ldsA[6 * 16384];  // 96 KB fp32 quarters
  __shared__ __attribute__((aligned(1024))) char ldsB[4 * 16384];  // 64 KB bf16 halves

  const int t = threadIdx.x;
  const int bs0 = blockIdx.x * BM;
  const int b = bs0 >> 11;  // / NS
  const int lane = t & 63;
  const int wid = t >> 6;
  const int wr = wid >> 1;   // 0..3: 64-row quarter of output (= A quarter)
  const int wc = wid & 1;    // 0..1: 128-col half of output (= B half)
  const int lrow = lane & 15;
  const int ko = lane >> 4;

  // staging maps (thread-linear LDS dest, inverse-swizzled global source)
  const int rowA = t >> 4;                   // 0..31 (A: 16 units/256B row)
  const int scolA = (t & 15) ^ (rowA & 15);  // col16 unit (4 floats)
  const int rowB = t >> 3;                   // 0..63 (B: 8 units/128B row)
  const int scolB = (t & 7) ^ (rowB & 7);    // col16 unit (8 bf16)

  // fragment read units (pre-swizzled; frag rows fi*16+lrow -> row&15 == lrow)
  const int sA00 = (ko * 2) ^ lrow, sA01 = (ko * 2 + 1) ^ lrow;
  const int sA10 = (8 + ko * 2) ^ lrow, sA11 = (8 + ko * 2 + 1) ^ lrow;
  const int sB0 = ko ^ (lrow & 7), sB1 = (4 + ko) ^ (lrow & 7);

  f32x4 acc[4][8];
#pragma unroll
  for (int mi = 0; mi < 4; ++mi)
#pragma unroll
    for (int ni = 0; ni < 8; ++ni) acc[mi][ni] = f32x4{0.f, 0.f, 0.f, 0.f};

  bf16x8 af[4][2], bfr[2][2];

#define STAGE_A(T, Q)                                                           \
  do {                                                                          \
    if ((T) < NTILES) {                                                         \
      const unsigned slot_ = (4u * (unsigned)(T) + (unsigned)(Q)) % 6u;         \
      char* d_ = ldsA + slot_ * 16384 + t * 16;                                 \
      const size_t r0_ = (size_t)(bs0 + (Q)*64 + rowA);                         \
      const int kf_ = ((T)&15) * 64 + scolA * 4;                                \
      glds16(keysf + r0_ * ND + kf_, d_);                                       \
      glds16(keysf + (r0_ + 32) * ND + kf_, d_ + 8192);                         \
    }                                                                           \
  } while (0)

#define STAGE_B(T, H)                                                           \
  do {                                                                          \
    if ((T) < NTILES) {                                                         \
      const unsigned slot_ = (2u * (unsigned)(T) + (unsigned)(H)) % 4u;         \
      char* d_ = ldsB + slot_ * 16384 + t * 16;                                 \
      const size_t r0_ = (size_t)(((T) >> 4) * 256 + (H)*128 + rowB);           \
      const int ke_ = (((T)&15) * 64) + scolB * 8;                              \
      glds16(W2b + r0_ * ND + ke_, d_);                                         \
      glds16(W2b + (r0_ + 64) * ND + ke_, d_ + 8192);                           \
    }                                                                           \
  } while (0)

#define SB_ __builtin_amdgcn_sched_barrier(0)
#define P1 __builtin_amdgcn_s_setprio(1)
#define P0 __builtin_amdgcn_s_setprio(0)
#define BAR __builtin_amdgcn_s_barrier()

  // PHASE P_ (0..3): stage -> [ph1: all 16 A-frag reads + cvt] -> 2 B-frags ->
  // BAR -> lgkm(0) -> 16 MFMA (mi 0..3 x nq 0..1, ni = P_*2+nq) ->
  // [ph4: vmcnt(0)] -> BAR.
#define PHASE(P_, STAGES)                                                       \
  do {                                                                          \
    STAGES;                                                                     \
    if ((P_) == 0) {                                                            \
      const char* Ab_ = ldsA + ((4u * (unsigned)tau + (unsigned)wr) % 6u) * 16384; \
      _Pragma("unroll") for (int mi = 0; mi < 4; ++mi) {                        \
        const int rb_ = (mi * 16 + lrow) * 256;                                 \
        f32x4 l0 = *reinterpret_cast<const f32x4*>(Ab_ + rb_ + sA00 * 16);      \
        f32x4 l1 = *reinterpret_cast<const f32x4*>(Ab_ + rb_ + sA01 * 16);      \
        f32x4 h0 = *reinterpret_cast<const f32x4*>(Ab_ + rb_ + sA10 * 16);      \
        f32x4 h1 = *reinterpret_cast<const f32x4*>(Ab_ + rb_ + sA11 * 16);      \
        _Pragma("unroll") for (int j = 0; j < 4; ++j) {                         \
          af[mi][0][j] = (__bf16)l0[j]; af[mi][0][4 + j] = (__bf16)l1[j];       \
          af[mi][1][j] = (__bf16)h0[j]; af[mi][1][4 + j] = (__bf16)h1[j];       \
        }                                                                       \
      }                                                                         \
    }                                                                           \
    {                                                                           \
      const char* Bb_ = ldsB + ((2u * (unsigned)tau + (unsigned)wc) % 4u) * 16384; \
      _Pragma("unroll") for (int nq = 0; nq < 2; ++nq) {                        \
        const int rb_ = (((P_)*2 + nq) * 16 + lrow) * 128;                      \
        bfr[nq][0] = *reinterpret_cast<const bf16x8*>(Bb_ + rb_ + sB0 * 16);    \
        bfr[nq][1] = *reinterpret_cast<const bf16x8*>(Bb_ + rb_ + sB1 * 16);    \
      }                                                                         \
    }                                                                           \
    BAR;                                                                        \
    asm volatile("s_waitcnt lgkmcnt(0)");                                       \
    SB_;                                                                        \
    P1;                                                                         \
    _Pragma("unroll") for (int mi = 0; mi < 4; ++mi)                            \
        _Pragma("unroll") for (int nq = 0; nq < 2; ++nq) {                      \
      acc[mi][(P_)*2 + nq] = __builtin_amdgcn_mfma_f32_16x16x32_bf16(           \
          af[mi][0], bfr[nq][0], acc[mi][(P_)*2 + nq], 0, 0, 0);                \
      acc[mi][(P_)*2 + nq] = __builtin_amdgcn_mfma_f32_16x16x32_bf16(           \
          af[mi][1], bfr[nq][1], acc[mi][(P_)*2 + nq], 0, 0, 0);                \
    }                                                                           \
    P0;                                                                         \
    if ((P_) == 3) {                                                            \
      asm volatile("s_waitcnt vmcnt(0)");                                       \
      SB_;                                                                      \
    }                                                                           \
    BAR;                                                                        \
  } while (0)

  // ---- prologue: full tile 0; drain once ----
  STAGE_A(0, 0);
  STAGE_A(0, 1);
  STAGE_A(0, 2);
  STAGE_A(0, 3);
  STAGE_B(0, 0);
  STAGE_B(0, 1);
  __syncthreads();

  for (int tau = 0; tau < NTILES; ++tau) {
    PHASE(0, { STAGE_A(tau + 1, 0); STAGE_A(tau + 1, 1); STAGE_B(tau + 1, 0); });
    PHASE(1, { STAGE_A(tau + 1, 2); STAGE_A(tau + 1, 3); STAGE_B(tau + 1, 1); });
    PHASE(2, {});
    PHASE(3, {});  // + vmcnt(0)

    // ---- per-a-tile epilogue: tanh + v-weight -> atomic scores ----
    if ((tau & 15) == 15) {
      const int a0 = (tau >> 4) * BN;
      float w1v[8], vv[8];
#pragma unroll
      for (int ni = 0; ni < 8; ++ni) {
        const int a = a0 + wc * 128 + ni * 16 + lrow;
        w1v[ni] = w1q[(size_t)b * NA + a];
        vv[ni] = vvec[a];
      }
#pragma unroll
      for (int mi = 0; mi < 4; ++mi)
#pragma unroll
        for (int r = 0; r < 4; ++r) {
          float p = 0.f;
#pragma unroll
          for (int ni = 0; ni < 8; ++ni) {
            const float x = acc[mi][ni][r] + w1v[ni];
            const float e = __expf(2.f * x);
            p += (1.f - 2.f * __builtin_amdgcn_rcpf(e + 1.f)) * vv[ni];
          }
          p += __shfl_xor(p, 1);
          p += __shfl_xor(p, 2);
          p += __shfl_xor(p, 4);
          p += __shfl_xor(p, 8);
          if (lrow == 0)
            atomicAdd(&scores[bs0 + wr * 64 + mi * 16 + ko * 4 + r], p);
        }
#pragma unroll
      for (int mi = 0; mi < 4; ++mi)
#pragma unroll
        for (int ni = 0; ni < 8; ++ni) acc[mi][ni] = f32x4{0.f, 0.f, 0.f, 0.f};
    }
  }

#undef STAGE_A
#undef STAGE_B
#undef PHASE
#undef SB_
#undef P1
#undef P0
#undef BAR
}

// ---------------- masked softmax ----------------
__global__ __launch_bounds__(256) void softmax_kernel(const float* __restrict__ scores,
                                                      const int* __restrict__ mask,
                                                      float* __restrict__ out) {
  const int b = blockIdx.x;
  const int t = threadIdx.x;
  float sc[8];
  float mx = -3.4e38f;
#pragma unroll
  for (int j = 0; j < 8; ++j) {
    int i = t + j * 256;
    float s = scores[b * NS + i];
    if (mask[b * NS + i] == 0) s -= MASK_NEG;
    sc[j] = s;
    mx = fmaxf(mx, s);
  }
#pragma unroll
  for (int off = 1; off < 64; off <<= 1) mx = fmaxf(mx, __shfl_xor(mx, off));
  __shared__ float redm[4];
  __shared__ float reds[4];
  if ((t & 63) == 0) redm[t >> 6] = mx;
  __syncthreads();
  mx = fmaxf(fmaxf(redm[0], redm[1]), fmaxf(redm[2], redm[3]));
  float e[8];
  float sum = 0.f;
#pragma unroll
  for (int j = 0; j < 8; ++j) {
    e[j] = __expf(sc[j] - mx);
    sum += e[j];
  }
#pragma unroll
  for (int off = 1; off < 64; off <<= 1) sum += __shfl_xor(sum, off);
  if ((t & 63) == 0) reds[t >> 6] = sum;
  __syncthreads();
  sum = reds[0] + reds[1] + reds[2] + reds[3];
  float inv = 1.f / sum;
#pragma unroll
  for (int j = 0; j < 8; ++j) out[b * NS + t + j * 256] = e[j] * inv;
}

extern "C" void kernel_launch(void* const* d_in, const int* in_sizes, int n_in,
                              void* d_out, int out_size, void* d_ws, size_t ws_size,
                              hipStream_t stream) {
  const float* q = (const float*)d_in[0];
  const float* keysf = (const float*)d_in[1];
  const int* mask = (const int*)d_in[2];
  const float* W1 = (const float*)d_in[3];
  const float* W2f = (const float*)d_in[4];
  const float* v = (const float*)d_in[5];
  float* out = (float*)d_out;

  float* scores = (float*)d_ws;                                 // 256 KB
  float* w1q = scores + NB * NS;                                // 128 KB
  __bf16* W2b = (__bf16*)(w1q + NB * NA);                       // 2 MB

  zero_f32<<<NB * NS / 256, 256, 0, stream>>>(scores, NB * NS);
  cvt_bf16<<<512, 256, 0, stream>>>(W2f, W2b, NA * ND / 8);
  w1q_kernel<<<dim3(NB, NA / 64), 256, 0, stream>>>(q, W1, w1q);
  score_gemm<<<NB * NS / BM, 512, 0, stream>>>(keysf, W2b, w1q, v, scores);
  softmax_kernel<<<NB, 256, 0, stream>>>(scores, mask, out);
}